// Round 1
// baseline (1373.757 us; speedup 1.0000x reference)
//
#include <hip/hip_runtime.h>
#include <hip/hip_bf16.h>
#include <math.h>

typedef __hip_bfloat16 bf16;

#define H_    64
#define W_    64
#define DIM   160
#define HEADS 5
#define KD    32
#define WS    14
#define NTOK  196            // WS*WS
#define NWIN  400            // 16 * 5 * 5
#define HIDDEN 640
#define EPS   1e-5f
#define NROW  (NWIN*NTOK)    // 78400
#define BATCH 16
#define L_    (H_*W_)        // 4096
#define MROW  (BATCH*L_)     // 65536

__device__ __forceinline__ float bf2f(bf16 v) { return __bfloat162float(v); }
__device__ __forceinline__ bf16  f2bf(float v) { return __float2bfloat16(v); }

// ---------------------------------------------------------------- LN kernels
// One 64-lane wave per row of 160 channels.
__global__ __launch_bounds__(64) void ln1_win_kernel(
    const float* __restrict__ x, const float* __restrict__ g,
    const float* __restrict__ b, bf16* __restrict__ xn)
{
    const int row = blockIdx.x;                 // window-token row, 0..78399
    const int win = row / NTOK, tok = row % NTOK;
    const int bb = win / 25, wr = (win % 25) / 5, wc = win % 5;
    const int th = tok / WS, tw = tok % WS;
    const int gh = wr * WS + th, gw = wc * WS + tw;
    const bool valid = (gh < H_) && (gw < W_);
    const float* xrow = x + ((size_t)bb * L_ + (size_t)gh * W_ + gw) * DIM;
    const int lane = threadIdx.x;
    float v0 = 0.f, v1 = 0.f, v2 = 0.f;
    if (valid) {
        v0 = xrow[lane];
        v1 = xrow[lane + 64];
        if (lane < 32) v2 = xrow[lane + 128];
    }
    float s  = v0 + v1 + v2;
    float sq = v0 * v0 + v1 * v1 + v2 * v2;
#pragma unroll
    for (int off = 32; off; off >>= 1) { s += __shfl_xor(s, off); sq += __shfl_xor(sq, off); }
    const float mean = s * (1.0f / DIM);
    const float var  = sq * (1.0f / DIM) - mean * mean;
    const float rs   = rsqrtf(var + EPS);
    bf16* orow = xn + (size_t)row * DIM;
    orow[lane]      = f2bf((v0 - mean) * rs * g[lane]      + b[lane]);
    orow[lane + 64] = f2bf((v1 - mean) * rs * g[lane + 64] + b[lane + 64]);
    if (lane < 32) orow[lane + 128] = f2bf((v2 - mean) * rs * g[lane + 128] + b[lane + 128]);
}

__global__ __launch_bounds__(64) void ln2_kernel(
    const float* __restrict__ x, const float* __restrict__ g,
    const float* __restrict__ b, bf16* __restrict__ xn)
{
    const int row = blockIdx.x;                 // 0..65535
    const float* xrow = x + (size_t)row * DIM;
    const int lane = threadIdx.x;
    float v0 = xrow[lane];
    float v1 = xrow[lane + 64];
    float v2 = (lane < 32) ? xrow[lane + 128] : 0.f;
    float s  = v0 + v1 + v2;
    float sq = v0 * v0 + v1 * v1 + v2 * v2;
#pragma unroll
    for (int off = 32; off; off >>= 1) { s += __shfl_xor(s, off); sq += __shfl_xor(sq, off); }
    const float mean = s * (1.0f / DIM);
    const float var  = sq * (1.0f / DIM) - mean * mean;
    const float rs   = rsqrtf(var + EPS);
    bf16* orow = xn + (size_t)row * DIM;
    orow[lane]      = f2bf((v0 - mean) * rs * g[lane]      + b[lane]);
    orow[lane + 64] = f2bf((v1 - mean) * rs * g[lane + 64] + b[lane + 64]);
    if (lane < 32) orow[lane + 128] = f2bf((v2 - mean) * rs * g[lane + 128] + b[lane + 128]);
}

// ---------------------------------------------------------------- GEMM
// C[m,n] = sum_k A[m,k] * B[n,k] + bias[n]   (A bf16 MxK, B fp32 NxK row-major)
// Tile 128x32, BK=16, 256 threads, 4x4 micro-tile per thread.
// EPI: 0 = store bf16        (qkv)
//      1 = crop/scatter + residual, fp32  (proj; extra = original x)
//      2 = exact GELU, store bf16          (fc1)
//      3 = add extra, store fp32           (fc2; extra = x2)
#define GBM 128
#define GBN 32
#define GBK 16

template <int EPI>
__global__ __launch_bounds__(256) void gemm_kernel(
    const bf16* __restrict__ A, const float* __restrict__ B,
    const float* __restrict__ bias, void* __restrict__ Cv,
    const float* __restrict__ extra, int M, int N, int K)
{
    __shared__ __attribute__((aligned(16))) float As[GBK][GBM + 4];
    __shared__ __attribute__((aligned(16))) float Bs[GBK][GBN + 4];
    const int tid = threadIdx.x;
    const int tx = tid & 7;          // 0..7  -> n micro
    const int ty = tid >> 3;         // 0..31 -> m micro
    const int m0 = blockIdx.y * GBM, n0 = blockIdx.x * GBN;
    float acc[4][4] = {};
    for (int k0 = 0; k0 < K; k0 += GBK) {
        {   // A tile: 128 rows x 16 k of bf16; each thread 8 contiguous bf16 (16B)
            const int mm = tid >> 1;
            const int kq = (tid & 1) * 8;
            const int gm = m0 + mm;
            int4 pk = make_int4(0, 0, 0, 0);
            if (gm < M) pk = *(const int4*)(A + (size_t)gm * K + k0 + kq);
            float f[8];
            f[0] = __uint_as_float(((unsigned)pk.x) << 16);
            f[1] = __uint_as_float(((unsigned)pk.x) & 0xffff0000u);
            f[2] = __uint_as_float(((unsigned)pk.y) << 16);
            f[3] = __uint_as_float(((unsigned)pk.y) & 0xffff0000u);
            f[4] = __uint_as_float(((unsigned)pk.z) << 16);
            f[5] = __uint_as_float(((unsigned)pk.z) & 0xffff0000u);
            f[6] = __uint_as_float(((unsigned)pk.w) << 16);
            f[7] = __uint_as_float(((unsigned)pk.w) & 0xffff0000u);
#pragma unroll
            for (int t = 0; t < 8; ++t) As[kq + t][mm] = f[t];
        }
        {   // B tile: 32 n x 16 k fp32; thread loads float2
            const int nn = tid >> 3;
            const int kq = (tid & 7) * 2;
            float2 v = *(const float2*)(B + (size_t)(n0 + nn) * K + k0 + kq);
            Bs[kq][nn] = v.x; Bs[kq + 1][nn] = v.y;
        }
        __syncthreads();
#pragma unroll
        for (int k = 0; k < GBK; ++k) {
            float4 av = *(const float4*)&As[k][ty * 4];
            float4 bv = *(const float4*)&Bs[k][tx * 4];
            float a[4] = { av.x, av.y, av.z, av.w };
            float c[4] = { bv.x, bv.y, bv.z, bv.w };
#pragma unroll
            for (int i = 0; i < 4; ++i)
#pragma unroll
                for (int j = 0; j < 4; ++j) acc[i][j] += a[i] * c[j];
        }
        __syncthreads();
    }
#pragma unroll
    for (int i = 0; i < 4; ++i) {
        const int m = m0 + ty * 4 + i;
        if (m >= M) continue;
#pragma unroll
        for (int j = 0; j < 4; ++j) {
            const int n = n0 + tx * 4 + j;
            float val = acc[i][j] + bias[n];
            if (EPI == 0) {
                ((bf16*)Cv)[(size_t)m * N + n] = f2bf(val);
            } else if (EPI == 1) {
                const int win = m / NTOK, tok = m % NTOK;
                const int bb = win / 25, wr = (win % 25) / 5, wc = win % 5;
                const int gh = wr * WS + tok / WS, gw = wc * WS + tok % WS;
                if (gh < H_ && gw < W_) {
                    const size_t off = ((size_t)bb * L_ + (size_t)gh * W_ + gw) * DIM + n;
                    ((float*)Cv)[off] = extra[off] + val;
                }
            } else if (EPI == 2) {
                const float ge = 0.5f * val * (1.0f + erff(val * 0.70710678118654752f));
                ((bf16*)Cv)[(size_t)m * N + n] = f2bf(ge);
            } else {
                const size_t off = (size_t)m * N + n;
                ((float*)Cv)[off] = extra[off] + val;
            }
        }
    }
}

// ---------------------------------------------------------------- attention
// One block per (window, head). 4 waves; each wave owns query i = t*4+wave.
__global__ __launch_bounds__(256) void attn_kernel(
    const bf16* __restrict__ qkv, const float* __restrict__ abias,
    const int* __restrict__ bidx, bf16* __restrict__ out)
{
    __shared__ __attribute__((aligned(16))) float q_s[NTOK][32];
    __shared__ __attribute__((aligned(16))) float k_s[NTOK][32];   // XOR-swizzled float4 slots
    __shared__ __attribute__((aligned(16))) float v_s[NTOK][32];
    __shared__ float bias_h[NTOK];
    __shared__ float p_s[4][200];
    const int win = blockIdx.x / HEADS;
    const int h   = blockIdx.x % HEADS;
    const int tid = threadIdx.x;
    for (int e = tid; e < NTOK * 96; e += 256) {
        const int t = e / 96, c = e % 96;
        const float val = bf2f(qkv[(size_t)(win * NTOK + t) * 480 + h * 96 + c]);
        if (c < 32) q_s[t][c] = val;
        else if (c < 64) { const int kk = c - 32; k_s[t][(((kk >> 2) ^ (t & 7)) << 2) | (kk & 3)] = val; }
        else v_s[t][c - 64] = val;
    }
    for (int e = tid; e < NTOK; e += 256) bias_h[e] = abias[h * NTOK + e];
    __syncthreads();
    const int wave = tid >> 6, lane = tid & 63;
    const float scale = 0.17677669529663687f;   // 1/sqrt(32)
    for (int t = 0; t < 49; ++t) {
        const int i = t * 4 + wave;
        float4 qr[8];
        const float4* qrow = (const float4*)q_s[i];
#pragma unroll
        for (int s = 0; s < 8; ++s) qr[s] = qrow[s];
        float sv[4];
#pragma unroll
        for (int u = 0; u < 4; ++u) {
            const int j = lane + u * 64;
            float val = -1e30f;
            if (j < NTOK) {
                const float4* krow = (const float4*)k_s[j];
                const int sw = j & 7;
                float acc = 0.f;
#pragma unroll
                for (int s = 0; s < 8; ++s) {
                    float4 kv = krow[s ^ sw];   // de-swizzle -> logical slot s
                    acc += qr[s].x * kv.x + qr[s].y * kv.y + qr[s].z * kv.z + qr[s].w * kv.w;
                }
                val = acc * scale + bias_h[bidx[i * NTOK + j]];
            }
            sv[u] = val;
        }
        float mymax = fmaxf(fmaxf(sv[0], sv[1]), fmaxf(sv[2], sv[3]));
#pragma unroll
        for (int off = 32; off; off >>= 1) mymax = fmaxf(mymax, __shfl_xor(mymax, off));
        float mysum = 0.f;
#pragma unroll
        for (int u = 0; u < 4; ++u) {
            const int j = lane + u * 64;
            if (j < NTOK) {
                const float p = expf(sv[u] - mymax);
                p_s[wave][j] = p;
                mysum += p;
            }
        }
#pragma unroll
        for (int off = 32; off; off >>= 1) mysum += __shfl_xor(mysum, off);
        // PV: lane = (jslice 0..7) * 8 + (dvec 0..7); each lane does a 4-wide dim slice
        const int dv = lane & 7;
        const int js = lane >> 3;
        float ox = 0.f, oy = 0.f, oz = 0.f, ow = 0.f;
        const int j0 = js * 25;
        const int j1 = (j0 + 25 < NTOK) ? (j0 + 25) : NTOK;
        for (int j = j0; j < j1; ++j) {
            const float p = p_s[wave][j];
            const float4 vv = *(const float4*)&v_s[j][dv << 2];
            ox += p * vv.x; oy += p * vv.y; oz += p * vv.z; ow += p * vv.w;
        }
#pragma unroll
        for (int off = 8; off <= 32; off <<= 1) {
            ox += __shfl_xor(ox, off); oy += __shfl_xor(oy, off);
            oz += __shfl_xor(oz, off); ow += __shfl_xor(ow, off);
        }
        if (js == 0) {
            const float inv = 1.0f / mysum;
            bf16* orow = out + (size_t)(win * NTOK + i) * DIM + h * KD + (dv << 2);
            orow[0] = f2bf(ox * inv); orow[1] = f2bf(oy * inv);
            orow[2] = f2bf(oz * inv); orow[3] = f2bf(ow * inv);
        }
    }
}

// ---------------------------------------------------------------- dw conv + BN
__global__ __launch_bounds__(256) void dwconv_bn_kernel(
    const float* __restrict__ xin, const float* __restrict__ cw,
    const float* __restrict__ bng, const float* __restrict__ bnb,
    float* __restrict__ xout)
{
    const int gid = blockIdx.x * 256 + threadIdx.x;
    const int c = gid % DIM;
    const int pos = gid / DIM;
    const int bb = pos / L_, hw = pos % L_;
    const int hh = hw / W_, ww = hw % W_;
    float acc = 0.f;
#pragma unroll
    for (int kh = -1; kh <= 1; ++kh) {
        const int ih = hh + kh;
        if (ih < 0 || ih >= H_) continue;
#pragma unroll
        for (int kw = -1; kw <= 1; ++kw) {
            const int iw = ww + kw;
            if (iw < 0 || iw >= W_) continue;
            acc += xin[((size_t)bb * L_ + (size_t)ih * W_ + iw) * DIM + c]
                 * cw[c * 9 + (kh + 1) * 3 + (kw + 1)];
        }
    }
    xout[gid] = acc * (bng[c] * rsqrtf(1.0f + EPS)) + bnb[c];
}

// ---------------------------------------------------------------- launch
extern "C" void kernel_launch(void* const* d_in, const int* in_sizes, int n_in,
                              void* d_out, int out_size, void* d_ws, size_t ws_size,
                              hipStream_t stream)
{
    const float* x      = (const float*)d_in[0];
    const float* ln1_g  = (const float*)d_in[1];
    const float* ln1_b  = (const float*)d_in[2];
    const float* qkv_w  = (const float*)d_in[3];
    const float* qkv_b  = (const float*)d_in[4];
    const float* proj_w = (const float*)d_in[5];
    const float* proj_b = (const float*)d_in[6];
    const float* abias  = (const float*)d_in[7];
    const float* conv_w = (const float*)d_in[8];
    const float* bn_g   = (const float*)d_in[9];
    const float* bn_b   = (const float*)d_in[10];
    const float* ln2_g  = (const float*)d_in[11];
    const float* ln2_b  = (const float*)d_in[12];
    const float* fc1_w  = (const float*)d_in[13];
    const float* fc1_b  = (const float*)d_in[14];
    const float* fc2_w  = (const float*)d_in[15];
    const float* fc2_b  = (const float*)d_in[16];
    const int*   bidx   = (const int*)d_in[17];

    char* ws = (char*)d_ws;
    // region plan (bytes):
    //   [0,          25,088,000)  xn   (bf16 78400x160)   -- dead after qkv gemm
    //   [25,088,000, 100,352,000) qkv  (bf16 78400x480)   -- dead after attn
    //   [0,          83,886,080)  h    (bf16 65536x640)   -- reuses xn+qkv region
    //   [100,352,000,125,440,000) attn_out (bf16 78400x160) -- dead after proj
    //   [100,352,000,121,323,520) xn2  (bf16 65536x160)   -- reuses attn_out
    //   [125,440,000,167,383,040) x1   (f32 65536x160)
    //   x2 lives in d_out (fully rewritten by the final gemm).
    bf16*  xn   = (bf16*)(ws);
    bf16*  qkv  = (bf16*)(ws + 25088000);
    bf16*  ao   = (bf16*)(ws + 100352000);
    bf16*  xn2  = (bf16*)(ws + 100352000);
    float* x1   = (float*)(ws + 125440000);
    bf16*  hbuf = (bf16*)(ws);
    float* x2   = (float*)d_out;
    float* outp = (float*)d_out;

    ln1_win_kernel<<<dim3(NROW), dim3(64), 0, stream>>>(x, ln1_g, ln1_b, xn);

    gemm_kernel<0><<<dim3(480 / GBN, (NROW + GBM - 1) / GBM), dim3(256), 0, stream>>>(
        xn, qkv_w, qkv_b, (void*)qkv, nullptr, NROW, 480, DIM);

    attn_kernel<<<dim3(NWIN * HEADS), dim3(256), 0, stream>>>(qkv, abias, bidx, ao);

    gemm_kernel<1><<<dim3(DIM / GBN, (NROW + GBM - 1) / GBM), dim3(256), 0, stream>>>(
        ao, proj_w, proj_b, (void*)x1, x, NROW, DIM, DIM);

    dwconv_bn_kernel<<<dim3(MROW * DIM / 256), dim3(256), 0, stream>>>(
        x1, conv_w, bn_g, bn_b, x2);

    ln2_kernel<<<dim3(MROW), dim3(64), 0, stream>>>(x2, ln2_g, ln2_b, xn2);

    gemm_kernel<2><<<dim3(HIDDEN / GBN, MROW / GBM), dim3(256), 0, stream>>>(
        xn2, fc1_w, fc1_b, (void*)hbuf, nullptr, MROW, HIDDEN, DIM);

    gemm_kernel<3><<<dim3(DIM / GBN, MROW / GBM), dim3(256), 0, stream>>>(
        hbuf, fc2_w, fc2_b, (void*)outp, x2, MROW, DIM, HIDDEN);
}

// Round 2
// 654.797 us; speedup vs baseline: 2.0980x; 2.0980x over previous
//
#include <hip/hip_runtime.h>
#include <hip/hip_bf16.h>
#include <math.h>

typedef __hip_bfloat16 bf16;
typedef unsigned short ushort;
typedef __attribute__((ext_vector_type(4))) float f32x4;
typedef __attribute__((ext_vector_type(8))) short s16x8;
typedef __attribute__((ext_vector_type(4))) short s16x4;

#define H_    64
#define W_    64
#define DIM   160
#define HEADS 5
#define KD    32
#define WS    14
#define NTOK  196
#define NWIN  400
#define HIDDEN 640
#define EPS   1e-5f
#define NROW  (NWIN*NTOK)    // 78400
#define BATCH 16
#define L_    (H_*W_)
#define MROW  (BATCH*L_)     // 65536

__device__ __forceinline__ float bf2f(ushort u) {
    return __uint_as_float(((unsigned)u) << 16);
}
__device__ __forceinline__ ushort f2bfbits(float f) {
    unsigned u = __float_as_uint(f);
    unsigned r = (u + 0x7fffu + ((u >> 16) & 1u)) >> 16;
    return (ushort)r;
}

// ---------------------------------------------------------------- bias table
// BT[h][key][query] = abias[h, bidx[query*196 + key]]
__global__ __launch_bounds__(256) void bias_pre_kernel(
    const float* __restrict__ abias, const int* __restrict__ bidx,
    float* __restrict__ BT, int n_off)
{
    const int idx = blockIdx.x * 256 + threadIdx.x;
    if (idx >= HEADS * NTOK * NTOK) return;
    const int h = idx / (NTOK * NTOK), r = idx % (NTOK * NTOK);
    const int k = r / NTOK, q = r % NTOK;
    BT[idx] = abias[h * n_off + bidx[q * NTOK + k]];
}

// ---------------------------------------------------------------- LN kernels
__global__ __launch_bounds__(64) void ln1_win_kernel(
    const float* __restrict__ x, const float* __restrict__ g,
    const float* __restrict__ b, ushort* __restrict__ xn)
{
    const int row = blockIdx.x;
    const int win = row / NTOK, tok = row % NTOK;
    const int bb = win / 25, wr = (win % 25) / 5, wc = win % 5;
    const int th = tok / WS, tw = tok % WS;
    const int gh = wr * WS + th, gw = wc * WS + tw;
    const bool valid = (gh < H_) && (gw < W_);
    const float* xrow = x + ((size_t)bb * L_ + (size_t)gh * W_ + gw) * DIM;
    const int lane = threadIdx.x;
    float v0 = 0.f, v1 = 0.f, v2 = 0.f;
    if (valid) {
        v0 = xrow[lane];
        v1 = xrow[lane + 64];
        if (lane < 32) v2 = xrow[lane + 128];
    }
    float s  = v0 + v1 + v2;
    float sq = v0 * v0 + v1 * v1 + v2 * v2;
#pragma unroll
    for (int off = 32; off; off >>= 1) { s += __shfl_xor(s, off); sq += __shfl_xor(sq, off); }
    const float mean = s * (1.0f / DIM);
    const float var  = sq * (1.0f / DIM) - mean * mean;
    const float rs   = rsqrtf(var + EPS);
    ushort* orow = xn + (size_t)row * DIM;
    orow[lane]      = f2bfbits((v0 - mean) * rs * g[lane]      + b[lane]);
    orow[lane + 64] = f2bfbits((v1 - mean) * rs * g[lane + 64] + b[lane + 64]);
    if (lane < 32) orow[lane + 128] = f2bfbits((v2 - mean) * rs * g[lane + 128] + b[lane + 128]);
}

__global__ __launch_bounds__(64) void ln2_kernel(
    const float* __restrict__ x, const float* __restrict__ g,
    const float* __restrict__ b, ushort* __restrict__ xn)
{
    const int row = blockIdx.x;
    const float* xrow = x + (size_t)row * DIM;
    const int lane = threadIdx.x;
    float v0 = xrow[lane];
    float v1 = xrow[lane + 64];
    float v2 = (lane < 32) ? xrow[lane + 128] : 0.f;
    float s  = v0 + v1 + v2;
    float sq = v0 * v0 + v1 * v1 + v2 * v2;
#pragma unroll
    for (int off = 32; off; off >>= 1) { s += __shfl_xor(s, off); sq += __shfl_xor(sq, off); }
    const float mean = s * (1.0f / DIM);
    const float var  = sq * (1.0f / DIM) - mean * mean;
    const float rs   = rsqrtf(var + EPS);
    ushort* orow = xn + (size_t)row * DIM;
    orow[lane]      = f2bfbits((v0 - mean) * rs * g[lane]      + b[lane]);
    orow[lane + 64] = f2bfbits((v1 - mean) * rs * g[lane + 64] + b[lane + 64]);
    if (lane < 32) orow[lane + 128] = f2bfbits((v2 - mean) * rs * g[lane + 128] + b[lane + 128]);
}

// ---------------------------------------------------------------- MFMA GEMM
// C[m,n] = sum_k A[m,k] * W[n,k] + bias[n].  A bf16-bits [M][K], W fp32 [N][K].
// BM=128, BN=160, BK=32. 4 waves; wave owns 32 rows (2 M-tiles) x 10 N-tiles.
#define GBM 128
#define GBN 160
#define GBK 32

template <int EPI>
__global__ __launch_bounds__(256) void gemm_mfma(
    const ushort* __restrict__ A, const float* __restrict__ W,
    const float* __restrict__ bias, void* __restrict__ Cv,
    const float* __restrict__ extra, int M, int N, int K)
{
    __shared__ ushort As[2][GBM][40];
    __shared__ ushort Bs[2][GBN][40];
    const int tid = threadIdx.x;
    const int wv = tid >> 6, ln = tid & 63;
    const int g = ln >> 4, l15 = ln & 15;
    const int m0 = blockIdx.y * GBM, n0 = blockIdx.x * GBN;
    const int nk = K / GBK;
    f32x4 acc[2][10] = {};

    const int arow = tid >> 1, ahalf = tid & 1;
    int agm = m0 + arow; if (agm >= M) agm = M - 1;

    int4 ra0, ra1;
    float4 rb0[4], rb1[4];

    // ---- load regs for k-step 0
    {
        const int4* ap = (const int4*)(A + (size_t)agm * K + ahalf * 16);
        ra0 = ap[0]; ra1 = ap[1];
        const float4* wp0 = (const float4*)(W + (size_t)(n0 + (tid >> 1)) * K + (tid & 1) * 16);
#pragma unroll
        for (int j = 0; j < 4; ++j) rb0[j] = wp0[j];
        if (tid < 64) {
            const int e = tid + 256;
            const float4* wp1 = (const float4*)(W + (size_t)(n0 + (e >> 1)) * K + (e & 1) * 16);
#pragma unroll
            for (int j = 0; j < 4; ++j) rb1[j] = wp1[j];
        }
    }
    // ---- write buf0
    {
        *(int4*)&As[0][arow][ahalf * 16]     = ra0;
        *(int4*)&As[0][arow][ahalf * 16 + 8] = ra1;
        ushort cb[16];
#pragma unroll
        for (int j = 0; j < 4; ++j) {
            cb[j*4+0] = f2bfbits(rb0[j].x); cb[j*4+1] = f2bfbits(rb0[j].y);
            cb[j*4+2] = f2bfbits(rb0[j].z); cb[j*4+3] = f2bfbits(rb0[j].w);
        }
        *(int4*)&Bs[0][tid >> 1][(tid & 1) * 16]     = *(int4*)&cb[0];
        *(int4*)&Bs[0][tid >> 1][(tid & 1) * 16 + 8] = *(int4*)&cb[8];
        if (tid < 64) {
            const int e = tid + 256;
#pragma unroll
            for (int j = 0; j < 4; ++j) {
                cb[j*4+0] = f2bfbits(rb1[j].x); cb[j*4+1] = f2bfbits(rb1[j].y);
                cb[j*4+2] = f2bfbits(rb1[j].z); cb[j*4+3] = f2bfbits(rb1[j].w);
            }
            *(int4*)&Bs[0][e >> 1][(e & 1) * 16]     = *(int4*)&cb[0];
            *(int4*)&Bs[0][e >> 1][(e & 1) * 16 + 8] = *(int4*)&cb[8];
        }
    }

    for (int s = 0; s < nk; ++s) {
        const int buf = s & 1;
        if (s + 1 < nk) {   // issue loads for s+1 (latency hidden under barrier+MFMA)
            const int ks = (s + 1) * GBK;
            const int4* ap = (const int4*)(A + (size_t)agm * K + ks + ahalf * 16);
            ra0 = ap[0]; ra1 = ap[1];
            const float4* wp0 = (const float4*)(W + (size_t)(n0 + (tid >> 1)) * K + ks + (tid & 1) * 16);
#pragma unroll
            for (int j = 0; j < 4; ++j) rb0[j] = wp0[j];
            if (tid < 64) {
                const int e = tid + 256;
                const float4* wp1 = (const float4*)(W + (size_t)(n0 + (e >> 1)) * K + ks + (e & 1) * 16);
#pragma unroll
                for (int j = 0; j < 4; ++j) rb1[j] = wp1[j];
            }
        }
        __syncthreads();
        // ---- compute on buf
        {
            s16x8 af0 = *(const s16x8*)&As[buf][wv * 32 + l15][g * 8];
            s16x8 af1 = *(const s16x8*)&As[buf][wv * 32 + 16 + l15][g * 8];
#pragma unroll
            for (int nt = 0; nt < 10; ++nt) {
                s16x8 bf = *(const s16x8*)&Bs[buf][nt * 16 + l15][g * 8];
                acc[0][nt] = __builtin_amdgcn_mfma_f32_16x16x32_bf16(af0, bf, acc[0][nt], 0, 0, 0);
                acc[1][nt] = __builtin_amdgcn_mfma_f32_16x16x32_bf16(af1, bf, acc[1][nt], 0, 0, 0);
            }
        }
        if (s + 1 < nk) {   // write buf^1
            const int nb = buf ^ 1;
            *(int4*)&As[nb][arow][ahalf * 16]     = ra0;
            *(int4*)&As[nb][arow][ahalf * 16 + 8] = ra1;
            ushort cb[16];
#pragma unroll
            for (int j = 0; j < 4; ++j) {
                cb[j*4+0] = f2bfbits(rb0[j].x); cb[j*4+1] = f2bfbits(rb0[j].y);
                cb[j*4+2] = f2bfbits(rb0[j].z); cb[j*4+3] = f2bfbits(rb0[j].w);
            }
            *(int4*)&Bs[nb][tid >> 1][(tid & 1) * 16]     = *(int4*)&cb[0];
            *(int4*)&Bs[nb][tid >> 1][(tid & 1) * 16 + 8] = *(int4*)&cb[8];
            if (tid < 64) {
                const int e = tid + 256;
#pragma unroll
                for (int j = 0; j < 4; ++j) {
                    cb[j*4+0] = f2bfbits(rb1[j].x); cb[j*4+1] = f2bfbits(rb1[j].y);
                    cb[j*4+2] = f2bfbits(rb1[j].z); cb[j*4+3] = f2bfbits(rb1[j].w);
                }
                *(int4*)&Bs[nb][e >> 1][(e & 1) * 16]     = *(int4*)&cb[0];
                *(int4*)&Bs[nb][e >> 1][(e & 1) * 16 + 8] = *(int4*)&cb[8];
            }
        }
    }

    // ---- epilogue
#pragma unroll
    for (int mt = 0; mt < 2; ++mt) {
#pragma unroll
        for (int nt = 0; nt < 10; ++nt) {
            const int n = n0 + nt * 16 + l15;
            const float bn = bias[n];
#pragma unroll
            for (int r = 0; r < 4; ++r) {
                const int m = m0 + wv * 32 + mt * 16 + g * 4 + r;
                if (m >= M) continue;
                const float val = acc[mt][nt][r] + bn;
                if (EPI == 0) {
                    ((ushort*)Cv)[(size_t)m * N + n] = f2bfbits(val);
                } else if (EPI == 1) {
                    const int win = m / NTOK, tok = m % NTOK;
                    const int bb = win / 25, wr = (win % 25) / 5, wc = win % 5;
                    const int gh = wr * WS + tok / WS, gw = wc * WS + tok % WS;
                    if (gh < H_ && gw < W_) {
                        const size_t off = ((size_t)bb * L_ + (size_t)gh * W_ + gw) * DIM + n;
                        ((float*)Cv)[off] = extra[off] + val;
                    }
                } else if (EPI == 2) {
                    const float ge = 0.5f * val * (1.0f + erff(val * 0.70710678118654752f));
                    ((ushort*)Cv)[(size_t)m * N + n] = f2bfbits(ge);
                } else {
                    const size_t off = (size_t)m * N + n;
                    ((float*)Cv)[off] = extra[off] + val;
                }
            }
        }
    }
}

// ---------------------------------------------------------------- attention
// Block = (window, head). 4 waves; wave handles Q-tiles qt = wv, wv+4, ...
// S^T = K . Q^T via mfma_16x16x32_bf16 (lane: query = l&15, keys = 16t+4g+r).
// O^T = V^T . P^T via mfma_16x16x16bf16_1k (P regs feed B-frag directly).
__global__ __launch_bounds__(256) void attn_mfma_kernel(
    const ushort* __restrict__ qkv, const float* __restrict__ biasT,
    ushort* __restrict__ out)
{
    __shared__ ushort Ks[208][40];
    __shared__ ushort VT[32][212];
    const int win = blockIdx.x / HEADS;
    const int h   = blockIdx.x % HEADS;
    const int tid = threadIdx.x;
    const size_t base = (size_t)win * NTOK;

    // stage K rows (bf16, 16B chunks), pad rows clamped (masked later)
    for (int e = tid; e < 208 * 4; e += 256) {
        const int row = e >> 2, part = e & 3;
        const int gr = row < NTOK ? row : NTOK - 1;
        const int4 p = *(const int4*)(qkv + (base + gr) * 480 + h * 96 + 32 + part * 8);
        *(int4*)&Ks[row][part * 8] = p;
    }
    // stage V^T with zero pad for keys >= 196
    for (int e = tid; e < 208 * 32; e += 256) {
        const int key = e >> 5, d = e & 31;
        VT[d][key] = (key < NTOK) ? qkv[(base + key) * 480 + h * 96 + 64 + d] : (ushort)0;
    }
    __syncthreads();

    const int wv = tid >> 6, ln = tid & 63, g = ln >> 4, l15 = ln & 15;
    const float scale = 0.17677669529663687f;   // 1/sqrt(32)
    const float* bp = biasT + (size_t)h * NTOK * NTOK;

    for (int qt = wv; qt < 13; qt += 4) {
        const int q0 = qt * 16;
        const int qr = q0 + l15;
        const int qc = qr < NTOK ? qr : NTOK - 1;
        const s16x8 qf = *(const s16x8*)(qkv + (base + qc) * 480 + h * 96 + g * 8);

        f32x4 S[13];
#pragma unroll
        for (int kt = 0; kt < 13; ++kt) {
            const s16x8 kf = *(const s16x8*)&Ks[kt * 16 + l15][g * 8];
            S[kt] = __builtin_amdgcn_mfma_f32_16x16x32_bf16(kf, qf, (f32x4){0.f,0.f,0.f,0.f}, 0, 0, 0);
        }
        // bias + scale + key-mask; per-lane max over 52 values
        float mx = -1e30f;
#pragma unroll
        for (int kt = 0; kt < 13; ++kt) {
            const int kb = kt * 16 + g * 4;
#pragma unroll
            for (int r = 0; r < 4; ++r) {
                const int key = kb + r;
                float sv;
                if (key < NTOK) sv = S[kt][r] * scale + bp[(size_t)key * NTOK + qc];
                else sv = -1e30f;
                S[kt][r] = sv;
                mx = fmaxf(mx, sv);
            }
        }
        mx = fmaxf(mx, __shfl_xor(mx, 16));
        mx = fmaxf(mx, __shfl_xor(mx, 32));

        float sum = 0.f;
        s16x4 P[13];
#pragma unroll
        for (int kt = 0; kt < 13; ++kt) {
            const float p0 = expf(S[kt][0] - mx);
            const float p1 = expf(S[kt][1] - mx);
            const float p2 = expf(S[kt][2] - mx);
            const float p3 = expf(S[kt][3] - mx);
            sum += (p0 + p1) + (p2 + p3);
            P[kt] = (s16x4){ (short)f2bfbits(p0), (short)f2bfbits(p1),
                             (short)f2bfbits(p2), (short)f2bfbits(p3) };
        }
        sum += __shfl_xor(sum, 16);
        sum += __shfl_xor(sum, 32);

        f32x4 o0 = {0.f,0.f,0.f,0.f}, o1 = {0.f,0.f,0.f,0.f};
#pragma unroll
        for (int kt = 0; kt < 13; ++kt) {
            const s16x4 vf0 = *(const s16x4*)&VT[l15][kt * 16 + g * 4];
            const s16x4 vf1 = *(const s16x4*)&VT[16 + l15][kt * 16 + g * 4];
            o0 = __builtin_amdgcn_mfma_f32_16x16x16bf16_1k(vf0, P[kt], o0, 0, 0, 0);
            o1 = __builtin_amdgcn_mfma_f32_16x16x16bf16_1k(vf1, P[kt], o1, 0, 0, 0);
        }
        if (qr < NTOK) {
            const float inv = 1.0f / sum;
            ushort* op = out + ((base + qr) * DIM + h * KD);
#pragma unroll
            for (int r = 0; r < 4; ++r) {
                op[g * 4 + r]      = f2bfbits(o0[r] * inv);
                op[16 + g * 4 + r] = f2bfbits(o1[r] * inv);
            }
        }
    }
}

// ---------------------------------------------------------------- dw conv + BN
__global__ __launch_bounds__(256) void dwconv_bn_kernel(
    const float* __restrict__ xin, const float* __restrict__ cw,
    const float* __restrict__ bng, const float* __restrict__ bnb,
    float* __restrict__ xout)
{
    const int gid = blockIdx.x * 256 + threadIdx.x;
    const int c = gid % DIM;
    const int pos = gid / DIM;
    const int bb = pos / L_, hw = pos % L_;
    const int hh = hw / W_, ww = hw % W_;
    float acc = 0.f;
#pragma unroll
    for (int kh = -1; kh <= 1; ++kh) {
        const int ih = hh + kh;
        if (ih < 0 || ih >= H_) continue;
#pragma unroll
        for (int kw = -1; kw <= 1; ++kw) {
            const int iw = ww + kw;
            if (iw < 0 || iw >= W_) continue;
            acc += xin[((size_t)bb * L_ + (size_t)ih * W_ + iw) * DIM + c]
                 * cw[c * 9 + (kh + 1) * 3 + (kw + 1)];
        }
    }
    xout[gid] = acc * (bng[c] * rsqrtf(1.0f + EPS)) + bnb[c];
}

// ---------------------------------------------------------------- launch
extern "C" void kernel_launch(void* const* d_in, const int* in_sizes, int n_in,
                              void* d_out, int out_size, void* d_ws, size_t ws_size,
                              hipStream_t stream)
{
    const float* x      = (const float*)d_in[0];
    const float* ln1_g  = (const float*)d_in[1];
    const float* ln1_b  = (const float*)d_in[2];
    const float* qkv_w  = (const float*)d_in[3];
    const float* qkv_b  = (const float*)d_in[4];
    const float* proj_w = (const float*)d_in[5];
    const float* proj_b = (const float*)d_in[6];
    const float* abias  = (const float*)d_in[7];
    const float* conv_w = (const float*)d_in[8];
    const float* bn_g   = (const float*)d_in[9];
    const float* bn_b   = (const float*)d_in[10];
    const float* ln2_g  = (const float*)d_in[11];
    const float* ln2_b  = (const float*)d_in[12];
    const float* fc1_w  = (const float*)d_in[13];
    const float* fc1_b  = (const float*)d_in[14];
    const float* fc2_w  = (const float*)d_in[15];
    const float* fc2_b  = (const float*)d_in[16];
    const int*   bidx   = (const int*)d_in[17];
    const int    n_off  = in_sizes[7] / HEADS;

    char* ws = (char*)d_ws;
    // [0,          25,088,000)  xn  bf16 78400x160   (dead after qkv gemm)
    // [25,088,000, 100,352,000) qkv bf16 78400x480   (dead after attn)
    // [0,          83,886,080)  h   bf16 65536x640   (reuses xn+qkv)
    // [100,352,000,125,440,000) ao  bf16 78400x160   (dead after proj) / xn2
    // [125,440,000,126,208,320) biasT f32 5x196x196  (read only during attn;
    //                            overlaps x1, which proj writes AFTER attn)
    // [125,440,000,167,383,040) x1  f32 65536x160    (dead after conv)
    ushort* xn    = (ushort*)(ws);
    ushort* qkv   = (ushort*)(ws + 25088000);
    ushort* ao    = (ushort*)(ws + 100352000);
    ushort* xn2   = (ushort*)(ws + 100352000);
    float*  biasT = (float*)(ws + 125440000);
    float*  x1    = (float*)(ws + 125440000);
    ushort* hbuf  = (ushort*)(ws);
    float*  x2    = (float*)d_out;
    float*  outp  = (float*)d_out;

    bias_pre_kernel<<<dim3((HEADS * NTOK * NTOK + 255) / 256), dim3(256), 0, stream>>>(
        abias, bidx, biasT, n_off);

    ln1_win_kernel<<<dim3(NROW), dim3(64), 0, stream>>>(x, ln1_g, ln1_b, xn);

    gemm_mfma<0><<<dim3(480 / GBN, (NROW + GBM - 1) / GBM), dim3(256), 0, stream>>>(
        xn, qkv_w, qkv_b, (void*)qkv, nullptr, NROW, 480, DIM);

    attn_mfma_kernel<<<dim3(NWIN * HEADS), dim3(256), 0, stream>>>(qkv, biasT, ao);

    gemm_mfma<1><<<dim3(DIM / GBN, (NROW + GBM - 1) / GBM), dim3(256), 0, stream>>>(
        ao, proj_w, proj_b, (void*)x1, x, NROW, DIM, DIM);

    dwconv_bn_kernel<<<dim3(MROW * DIM / 256), dim3(256), 0, stream>>>(
        x1, conv_w, bn_g, bn_b, x2);

    ln2_kernel<<<dim3(MROW), dim3(64), 0, stream>>>(x2, ln2_g, ln2_b, xn2);

    gemm_mfma<2><<<dim3(HIDDEN / GBN, MROW / GBM), dim3(256), 0, stream>>>(
        xn2, fc1_w, fc1_b, (void*)hbuf, nullptr, MROW, HIDDEN, DIM);

    gemm_mfma<3><<<dim3(DIM / GBN, MROW / GBM), dim3(256), 0, stream>>>(
        hbuf, fc2_w, fc2_b, (void*)outp, x2, MROW, DIM, HIDDEN);
}

// Round 3
// 449.322 us; speedup vs baseline: 3.0574x; 1.4573x over previous
//
#include <hip/hip_runtime.h>
#include <hip/hip_bf16.h>
#include <math.h>

typedef unsigned short ushort;
typedef __attribute__((ext_vector_type(4))) float f32x4;
typedef __attribute__((ext_vector_type(8))) short s16x8;
typedef __attribute__((ext_vector_type(4))) short s16x4;
typedef __attribute__((ext_vector_type(4))) ushort u16x4;

#define H_    64
#define W_    64
#define DIM   160
#define HEADS 5
#define KD    32
#define WS    14
#define NTOK  196
#define NWIN  400
#define HIDDEN 640
#define EPS   1e-5f
#define NROW  (NWIN*NTOK)    // 78400
#define BATCH 16
#define L_    (H_*W_)
#define MROW  (BATCH*L_)     // 65536

#if __has_builtin(__builtin_amdgcn_exp2f)
#define EXP2(x) __builtin_amdgcn_exp2f(x)
#else
#define EXP2(x) exp2f(x)
#endif

__device__ __forceinline__ ushort f2bfbits(float f) {
    unsigned u = __float_as_uint(f);
    unsigned r = (u + 0x7fffu + ((u >> 16) & 1u)) >> 16;
    return (ushort)r;
}

// ---------------------------------------------------------------- pre kernel
// Converts all weights to bf16, builds BN-folded transposed conv weights, and
// the transposed+prescaled bias table biasT[h][q][key] = bias * sqrt(32).
__global__ __launch_bounds__(256) void pre_kernel(
    const float* __restrict__ qkv_w, const float* __restrict__ proj_w,
    const float* __restrict__ fc1_w, const float* __restrict__ fc2_w,
    const float* __restrict__ conv_w, const float* __restrict__ bn_g,
    const float* __restrict__ abias, const int* __restrict__ bidx,
    ushort* __restrict__ wb, float* __restrict__ cwT,
    float* __restrict__ biasT, int n_off)
{
    const int gid = blockIdx.x * 256 + threadIdx.x;
    if (gid < 19200) {
        float4 v = ((const float4*)qkv_w)[gid];
        u16x4 o = { f2bfbits(v.x), f2bfbits(v.y), f2bfbits(v.z), f2bfbits(v.w) };
        *(u16x4*)(wb + gid * 4) = o;
    } else if (gid < 25600) {
        const int i = gid - 19200;
        float4 v = ((const float4*)proj_w)[i];
        u16x4 o = { f2bfbits(v.x), f2bfbits(v.y), f2bfbits(v.z), f2bfbits(v.w) };
        *(u16x4*)(wb + 76800 + i * 4) = o;
    } else if (gid < 51200) {
        const int i = gid - 25600;
        float4 v = ((const float4*)fc1_w)[i];
        u16x4 o = { f2bfbits(v.x), f2bfbits(v.y), f2bfbits(v.z), f2bfbits(v.w) };
        *(u16x4*)(wb + 102400 + i * 4) = o;
    } else if (gid < 76800) {
        const int i = gid - 51200;
        float4 v = ((const float4*)fc2_w)[i];
        u16x4 o = { f2bfbits(v.x), f2bfbits(v.y), f2bfbits(v.z), f2bfbits(v.w) };
        *(u16x4*)(wb + 204800 + i * 4) = o;
    } else if (gid < 77160) {
        const int i = gid - 76800;
        const int t = i / 40, c4 = (i % 40) * 4;
#pragma unroll
        for (int j = 0; j < 4; ++j) {
            const int c = c4 + j;
            cwT[t * DIM + c] = conv_w[c * 9 + t] * bn_g[c] * rsqrtf(1.0f + EPS);
        }
    } else if (gid < 269240) {
        const int i = gid - 77160;
        const int h = i / (NTOK * NTOK), r = i % (NTOK * NTOK);
        const int q = r / NTOK, k = r % NTOK;
        biasT[i] = abias[h * n_off + bidx[q * NTOK + k]] * 5.656854249492381f;
    }
}

// ---------------------------------------------------------------- LN kernels
__global__ __launch_bounds__(256) void ln1_win_kernel(
    const float* __restrict__ x, const float* __restrict__ g,
    const float* __restrict__ b, ushort* __restrict__ xn)
{
    const int row = blockIdx.x * 4 + (threadIdx.x >> 6);
    const int win = row / NTOK, tok = row % NTOK;
    const int bb = win / 25, wr = (win % 25) / 5, wc = win % 5;
    const int gh = wr * WS + tok / WS, gw = wc * WS + tok % WS;
    const bool valid = (gh < H_) && (gw < W_);
    const float* xrow = x + ((size_t)bb * L_ + (size_t)gh * W_ + gw) * DIM;
    const int lane = threadIdx.x & 63;
    float v0 = 0.f, v1 = 0.f, v2 = 0.f;
    if (valid) {
        v0 = xrow[lane];
        v1 = xrow[lane + 64];
        if (lane < 32) v2 = xrow[lane + 128];
    }
    float s  = v0 + v1 + v2;
    float sq = v0 * v0 + v1 * v1 + v2 * v2;
#pragma unroll
    for (int off = 32; off; off >>= 1) { s += __shfl_xor(s, off); sq += __shfl_xor(sq, off); }
    const float mean = s * (1.0f / DIM);
    const float var  = sq * (1.0f / DIM) - mean * mean;
    const float rs   = rsqrtf(var + EPS);
    ushort* orow = xn + (size_t)row * DIM;
    orow[lane]      = f2bfbits((v0 - mean) * rs * g[lane]      + b[lane]);
    orow[lane + 64] = f2bfbits((v1 - mean) * rs * g[lane + 64] + b[lane + 64]);
    if (lane < 32) orow[lane + 128] = f2bfbits((v2 - mean) * rs * g[lane + 128] + b[lane + 128]);
}

__global__ __launch_bounds__(256) void ln2_kernel(
    const float* __restrict__ x, const float* __restrict__ g,
    const float* __restrict__ b, ushort* __restrict__ xn)
{
    const int row = blockIdx.x * 4 + (threadIdx.x >> 6);
    const float* xrow = x + (size_t)row * DIM;
    const int lane = threadIdx.x & 63;
    float v0 = xrow[lane];
    float v1 = xrow[lane + 64];
    float v2 = (lane < 32) ? xrow[lane + 128] : 0.f;
    float s  = v0 + v1 + v2;
    float sq = v0 * v0 + v1 * v1 + v2 * v2;
#pragma unroll
    for (int off = 32; off; off >>= 1) { s += __shfl_xor(s, off); sq += __shfl_xor(sq, off); }
    const float mean = s * (1.0f / DIM);
    const float var  = sq * (1.0f / DIM) - mean * mean;
    const float rs   = rsqrtf(var + EPS);
    ushort* orow = xn + (size_t)row * DIM;
    orow[lane]      = f2bfbits((v0 - mean) * rs * g[lane]      + b[lane]);
    orow[lane + 64] = f2bfbits((v1 - mean) * rs * g[lane + 64] + b[lane + 64]);
    if (lane < 32) orow[lane + 128] = f2bfbits((v2 - mean) * rs * g[lane + 128] + b[lane + 128]);
}

// ---------------------------------------------------------------- MFMA GEMM
// C[m,n] = sum_k A[m,k] * Wb[n,k] + bias[n].  A, Wb bf16-bits.
#define GBM 128
#define GBN 160
#define GBK 32

template <int EPI>
__global__ __launch_bounds__(256) void gemm_mfma(
    const ushort* __restrict__ A, const ushort* __restrict__ Wb,
    const float* __restrict__ bias, void* __restrict__ Cv,
    const float* __restrict__ extra, int M, int N, int K)
{
    __shared__ ushort As[2][GBM][40];
    __shared__ ushort Bs[2][GBN][40];
    const int tid = threadIdx.x;
    const int wv = tid >> 6, ln = tid & 63;
    const int g = ln >> 4, l15 = ln & 15;
    const int m0 = blockIdx.y * GBM, n0 = blockIdx.x * GBN;
    const int nk = K / GBK;
    f32x4 acc[2][10] = {};

    const int arow = tid >> 1, ahalf = tid & 1;
    int agm = m0 + arow; if (agm >= M) agm = M - 1;
    const ushort* Aptr = A + (size_t)agm * K + ahalf * 16;
    const ushort* B0p  = Wb + (size_t)(n0 + (tid >> 1)) * K + (tid & 1) * 16;
    const ushort* B1p  = Wb + (size_t)(n0 + 128 + (tid >> 1)) * K + (tid & 1) * 16;

    int4 ra0, ra1, rb0a, rb0b, rb1a = {}, rb1b = {};
#define GLOAD(ks)  do { \
        ra0  = *(const int4*)(Aptr + (ks));      ra1  = *(const int4*)(Aptr + (ks) + 8); \
        rb0a = *(const int4*)(B0p + (ks));       rb0b = *(const int4*)(B0p + (ks) + 8); \
        if (tid < 64) { rb1a = *(const int4*)(B1p + (ks)); rb1b = *(const int4*)(B1p + (ks) + 8); } \
    } while (0)
#define LWRITE(nb) do { \
        *(int4*)&As[nb][arow][ahalf * 16]            = ra0; \
        *(int4*)&As[nb][arow][ahalf * 16 + 8]        = ra1; \
        *(int4*)&Bs[nb][tid >> 1][(tid & 1) * 16]    = rb0a; \
        *(int4*)&Bs[nb][tid >> 1][(tid & 1) * 16 + 8]= rb0b; \
        if (tid < 64) { \
            *(int4*)&Bs[nb][128 + (tid >> 1)][(tid & 1) * 16]     = rb1a; \
            *(int4*)&Bs[nb][128 + (tid >> 1)][(tid & 1) * 16 + 8] = rb1b; \
        } \
    } while (0)

    GLOAD(0);
    LWRITE(0);
    for (int s = 0; s < nk; ++s) {
        const int buf = s & 1;
        if (s + 1 < nk) GLOAD((s + 1) * GBK);
        __syncthreads();
        {
            s16x8 af0 = *(const s16x8*)&As[buf][wv * 32 + l15][g * 8];
            s16x8 af1 = *(const s16x8*)&As[buf][wv * 32 + 16 + l15][g * 8];
#pragma unroll
            for (int nt = 0; nt < 10; ++nt) {
                s16x8 bf = *(const s16x8*)&Bs[buf][nt * 16 + l15][g * 8];
                acc[0][nt] = __builtin_amdgcn_mfma_f32_16x16x32_bf16(af0, bf, acc[0][nt], 0, 0, 0);
                acc[1][nt] = __builtin_amdgcn_mfma_f32_16x16x32_bf16(af1, bf, acc[1][nt], 0, 0, 0);
            }
        }
        if (s + 1 < nk) LWRITE(buf ^ 1);
    }
#undef GLOAD
#undef LWRITE

#pragma unroll
    for (int mt = 0; mt < 2; ++mt) {
#pragma unroll
        for (int nt = 0; nt < 10; ++nt) {
            const int n = n0 + nt * 16 + l15;
            const float bn = bias[n];
#pragma unroll
            for (int r = 0; r < 4; ++r) {
                const int m = m0 + wv * 32 + mt * 16 + g * 4 + r;
                if (m >= M) continue;
                const float val = acc[mt][nt][r] + bn;
                if (EPI == 0) {
                    ((ushort*)Cv)[(size_t)m * N + n] = f2bfbits(val);
                } else if (EPI == 1) {
                    const int win = m / NTOK, tok = m % NTOK;
                    const int bb = win / 25, wr = (win % 25) / 5, wc = win % 5;
                    const int gh = wr * WS + tok / WS, gw = wc * WS + tok % WS;
                    if (gh < H_ && gw < W_) {
                        const size_t off = ((size_t)bb * L_ + (size_t)gh * W_ + gw) * DIM + n;
                        ((float*)Cv)[off] = extra[off] + val;
                    }
                } else if (EPI == 2) {
                    const float ge = 0.5f * val * (1.0f + erff(val * 0.70710678118654752f));
                    ((ushort*)Cv)[(size_t)m * N + n] = f2bfbits(ge);
                } else {
                    const size_t off = (size_t)m * N + n;
                    ((float*)Cv)[off] = extra[off] + val;
                }
            }
        }
    }
}

// ---------------------------------------------------------------- attention
// Block = (window, head). S^T = K.Q^T via mfma_16x16x32_bf16 with the bias
// table (prescaled by sqrt(32)) loaded directly into the accumulator.
// Softmax in exp2 domain (native v_exp_f32). O^T = V^T.P^T via 16x16x16.
__global__ __launch_bounds__(256) void attn_mfma_kernel(
    const ushort* __restrict__ qkv, const float* __restrict__ biasT,
    ushort* __restrict__ out)
{
    __shared__ ushort Ks[208][40];
    __shared__ ushort VT[32][212];
    const int win = blockIdx.x / HEADS;
    const int h   = blockIdx.x % HEADS;
    const int tid = threadIdx.x;
    const size_t base = (size_t)win * NTOK;
    const ushort* qbase = qkv + base * 480 + h * 96;

    for (int e = tid; e < 208 * 4; e += 256) {
        const int row = e >> 2, part = e & 3;
        const int gr = row < NTOK ? row : NTOK - 1;
        *(int4*)&Ks[row][part * 8] = *(const int4*)(qbase + (size_t)gr * 480 + 32 + part * 8);
    }
    for (int e = tid; e < NTOK * 4; e += 256) {
        const int key = e >> 2, part = e & 3;
        int4 p = *(const int4*)(qbase + (size_t)key * 480 + 64 + part * 8);
        const ushort* u = (const ushort*)&p;
#pragma unroll
        for (int j = 0; j < 8; ++j) VT[part * 8 + j][key] = u[j];
    }
    for (int e = tid; e < 12 * 32; e += 256) VT[e & 31][NTOK + (e >> 5)] = 0;
    __syncthreads();

    const int wv = tid >> 6, ln = tid & 63, g = ln >> 4, l15 = ln & 15;
    const float cs = 0.17677669529663687f * 1.4426950408889634f;  // scale*log2e

    for (int qt = wv; qt < 13; qt += 4) {
        const int qr = qt * 16 + l15;
        const int qc = qr < NTOK ? qr : NTOK - 1;
        const s16x8 qf = *(const s16x8*)(qbase + (size_t)qc * 480 + g * 8);
        const float* bq = biasT + ((size_t)h * NTOK + qc) * NTOK;

        f32x4 S[13];
#pragma unroll
        for (int kt = 0; kt < 13; ++kt)
            S[kt] = *(const f32x4*)(bq + kt * 16 + g * 4);
#pragma unroll
        for (int kt = 0; kt < 13; ++kt) {
            const s16x8 kf = *(const s16x8*)&Ks[kt * 16 + l15][g * 8];
            S[kt] = __builtin_amdgcn_mfma_f32_16x16x32_bf16(kf, qf, S[kt], 0, 0, 0);
        }
        float mx = -1e30f;
#pragma unroll
        for (int kt = 0; kt < 13; ++kt) {
            const int kb = kt * 16 + g * 4;
#pragma unroll
            for (int r = 0; r < 4; ++r) {
                const float sv = (kb + r < NTOK) ? S[kt][r] * cs : -1e30f;
                S[kt][r] = sv;
                mx = fmaxf(mx, sv);
            }
        }
        mx = fmaxf(mx, __shfl_xor(mx, 16));
        mx = fmaxf(mx, __shfl_xor(mx, 32));

        float sum = 0.f;
        s16x4 P[13];
#pragma unroll
        for (int kt = 0; kt < 13; ++kt) {
            const float p0 = EXP2(S[kt][0] - mx);
            const float p1 = EXP2(S[kt][1] - mx);
            const float p2 = EXP2(S[kt][2] - mx);
            const float p3 = EXP2(S[kt][3] - mx);
            sum += (p0 + p1) + (p2 + p3);
            P[kt] = (s16x4){ (short)f2bfbits(p0), (short)f2bfbits(p1),
                             (short)f2bfbits(p2), (short)f2bfbits(p3) };
        }
        sum += __shfl_xor(sum, 16);
        sum += __shfl_xor(sum, 32);

        f32x4 o0 = {0.f,0.f,0.f,0.f}, o1 = {0.f,0.f,0.f,0.f};
#pragma unroll
        for (int kt = 0; kt < 13; ++kt) {
            const s16x4 vf0 = *(const s16x4*)&VT[l15][kt * 16 + g * 4];
            const s16x4 vf1 = *(const s16x4*)&VT[16 + l15][kt * 16 + g * 4];
            o0 = __builtin_amdgcn_mfma_f32_16x16x16bf16_1k(vf0, P[kt], o0, 0, 0, 0);
            o1 = __builtin_amdgcn_mfma_f32_16x16x16bf16_1k(vf1, P[kt], o1, 0, 0, 0);
        }
        if (qr < NTOK) {
            const float inv = 1.0f / sum;
            ushort* op = out + (base + qr) * DIM + h * KD;
            u16x4 w0 = { f2bfbits(o0[0] * inv), f2bfbits(o0[1] * inv),
                         f2bfbits(o0[2] * inv), f2bfbits(o0[3] * inv) };
            u16x4 w1 = { f2bfbits(o1[0] * inv), f2bfbits(o1[1] * inv),
                         f2bfbits(o1[2] * inv), f2bfbits(o1[3] * inv) };
            *(u16x4*)(op + g * 4)      = w0;
            *(u16x4*)(op + 16 + g * 4) = w1;
        }
    }
}

// ---------------------------------------------------------------- dw conv + BN
// cwT[tap][c] is pre-scaled by bn_g*rsqrt(1+eps); float4 over channels.
__global__ __launch_bounds__(256) void dwconv_bn_kernel(
    const float* __restrict__ xin, const float* __restrict__ cwT,
    const float* __restrict__ bnb, float* __restrict__ xout)
{
    const int gid = blockIdx.x * 256 + threadIdx.x;   // MROW*40
    const int pos = gid / 40, c4 = (gid % 40) * 4;
    const int bb = pos >> 12, hw = pos & 4095;
    const int hh = hw >> 6, ww = hw & 63;
    float4 acc = *(const float4*)&bnb[c4];
#pragma unroll
    for (int kh = -1; kh <= 1; ++kh) {
        const int ih = hh + kh;
        if (ih < 0 || ih >= H_) continue;
#pragma unroll
        for (int kw = -1; kw <= 1; ++kw) {
            const int iw = ww + kw;
            if (iw < 0 || iw >= W_) continue;
            const float4 xv = *(const float4*)&xin[((size_t)(bb << 12) + (ih << 6) + iw) * DIM + c4];
            const float4 wv = *(const float4*)&cwT[((kh + 1) * 3 + (kw + 1)) * DIM + c4];
            acc.x = fmaf(xv.x, wv.x, acc.x);
            acc.y = fmaf(xv.y, wv.y, acc.y);
            acc.z = fmaf(xv.z, wv.z, acc.z);
            acc.w = fmaf(xv.w, wv.w, acc.w);
        }
    }
    *(float4*)&xout[(size_t)pos * DIM + c4] = acc;
}

// ---------------------------------------------------------------- launch
extern "C" void kernel_launch(void* const* d_in, const int* in_sizes, int n_in,
                              void* d_out, int out_size, void* d_ws, size_t ws_size,
                              hipStream_t stream)
{
    const float* x      = (const float*)d_in[0];
    const float* ln1_g  = (const float*)d_in[1];
    const float* ln1_b  = (const float*)d_in[2];
    const float* qkv_w  = (const float*)d_in[3];
    const float* qkv_b  = (const float*)d_in[4];
    const float* proj_w = (const float*)d_in[5];
    const float* proj_b = (const float*)d_in[6];
    const float* abias  = (const float*)d_in[7];
    const float* conv_w = (const float*)d_in[8];
    const float* bn_g   = (const float*)d_in[9];
    const float* bn_b   = (const float*)d_in[10];
    const float* ln2_g  = (const float*)d_in[11];
    const float* ln2_b  = (const float*)d_in[12];
    const float* fc1_w  = (const float*)d_in[13];
    const float* fc1_b  = (const float*)d_in[14];
    const float* fc2_w  = (const float*)d_in[15];
    const float* fc2_b  = (const float*)d_in[16];
    const int*   bidx   = (const int*)d_in[17];
    const int    n_off  = in_sizes[7] / HEADS;

    char* ws = (char*)d_ws;
    // [0,          25,088,000)  xn  bf16 78400x160   (dead after qkv gemm)
    // [25,088,000, 100,352,000) qkv bf16 78400x480   (dead after attn)
    // [0,          83,886,080)  h   bf16 65536x640   (reuses xn+qkv)
    // [100,352,000,125,440,000) ao  bf16 78400x160   (dead after proj) / xn2
    // [125,440,000,126,208,320) biasT f32 5x196x196  (overlaps x1; attn reads
    //                            it before proj writes x1)
    // [125,440,000,167,383,040) x1  f32 65536x160    (dead after conv)
    // [167,383,040,167,997,440) wb  bf16 weights (qkv|proj|fc1|fc2)
    // [167,997,440,168,003,200) cwT f32 9x160 (BN-folded)
    ushort* xn    = (ushort*)(ws);
    ushort* qkv   = (ushort*)(ws + 25088000);
    ushort* ao    = (ushort*)(ws + 100352000);
    ushort* xn2   = (ushort*)(ws + 100352000);
    float*  biasT = (float*)(ws + 125440000);
    float*  x1    = (float*)(ws + 125440000);
    ushort* hbuf  = (ushort*)(ws);
    ushort* wb    = (ushort*)(ws + 167383040);
    float*  cwT   = (float*)(ws + 167997440);
    float*  x2    = (float*)d_out;
    float*  outp  = (float*)d_out;

    pre_kernel<<<dim3(1052), dim3(256), 0, stream>>>(
        qkv_w, proj_w, fc1_w, fc2_w, conv_w, bn_g, abias, bidx, wb, cwT, biasT, n_off);

    ln1_win_kernel<<<dim3(NROW / 4), dim3(256), 0, stream>>>(x, ln1_g, ln1_b, xn);

    gemm_mfma<0><<<dim3(480 / GBN, (NROW + GBM - 1) / GBM), dim3(256), 0, stream>>>(
        xn, wb, qkv_b, (void*)qkv, nullptr, NROW, 480, DIM);

    attn_mfma_kernel<<<dim3(NWIN * HEADS), dim3(256), 0, stream>>>(qkv, biasT, ao);

    gemm_mfma<1><<<dim3(DIM / GBN, (NROW + GBM - 1) / GBM), dim3(256), 0, stream>>>(
        ao, wb + 76800, proj_b, (void*)x1, x, NROW, DIM, DIM);

    dwconv_bn_kernel<<<dim3(MROW * 40 / 256), dim3(256), 0, stream>>>(
        x1, cwT, bn_b, x2);

    ln2_kernel<<<dim3(MROW / 4), dim3(256), 0, stream>>>(x2, ln2_g, ln2_b, xn2);

    gemm_mfma<2><<<dim3(HIDDEN / GBN, MROW / GBM), dim3(256), 0, stream>>>(
        xn2, wb + 102400, fc1_b, (void*)hbuf, nullptr, MROW, HIDDEN, DIM);

    gemm_mfma<3><<<dim3(DIM / GBN, MROW / GBM), dim3(256), 0, stream>>>(
        hbuf, wb + 204800, fc2_b, (void*)outp, x2, MROW, DIM, HIDDEN);
}

// Round 4
// 388.480 us; speedup vs baseline: 3.5362x; 1.1566x over previous
//
#include <hip/hip_runtime.h>
#include <hip/hip_bf16.h>
#include <math.h>

typedef unsigned short ushort;
typedef __attribute__((ext_vector_type(4))) float f32x4;
typedef __attribute__((ext_vector_type(8))) short s16x8;
typedef __attribute__((ext_vector_type(4))) short s16x4;
typedef __attribute__((ext_vector_type(4))) ushort u16x4;

#define H_    64
#define W_    64
#define DIM   160
#define HEADS 5
#define KD    32
#define WS    14
#define NTOK  196
#define NWIN  400
#define HIDDEN 640
#define EPS   1e-5f
#define NROW  (NWIN*NTOK)    // 78400
#define BATCH 16
#define L_    (H_*W_)
#define MROW  (BATCH*L_)     // 65536

#if __has_builtin(__builtin_amdgcn_exp2f)
#define EXP2(x) __builtin_amdgcn_exp2f(x)
#else
#define EXP2(x) exp2f(x)
#endif

__device__ __forceinline__ ushort f2bfbits(float f) {
    unsigned u = __float_as_uint(f);
    unsigned r = (u + 0x7fffu + ((u >> 16) & 1u)) >> 16;
    return (ushort)r;
}

// ---------------------------------------------------------------- pre kernel
__global__ __launch_bounds__(256) void pre_kernel(
    const float* __restrict__ qkv_w, const float* __restrict__ proj_w,
    const float* __restrict__ fc1_w, const float* __restrict__ fc2_w,
    const float* __restrict__ conv_w, const float* __restrict__ bn_g,
    const float* __restrict__ abias, const int* __restrict__ bidx,
    ushort* __restrict__ wb, float* __restrict__ cwT,
    float* __restrict__ biasT, int n_off)
{
    const int gid = blockIdx.x * 256 + threadIdx.x;
    if (gid < 19200) {
        float4 v = ((const float4*)qkv_w)[gid];
        u16x4 o = { f2bfbits(v.x), f2bfbits(v.y), f2bfbits(v.z), f2bfbits(v.w) };
        *(u16x4*)(wb + gid * 4) = o;
    } else if (gid < 25600) {
        const int i = gid - 19200;
        float4 v = ((const float4*)proj_w)[i];
        u16x4 o = { f2bfbits(v.x), f2bfbits(v.y), f2bfbits(v.z), f2bfbits(v.w) };
        *(u16x4*)(wb + 76800 + i * 4) = o;
    } else if (gid < 51200) {
        const int i = gid - 25600;
        float4 v = ((const float4*)fc1_w)[i];
        u16x4 o = { f2bfbits(v.x), f2bfbits(v.y), f2bfbits(v.z), f2bfbits(v.w) };
        *(u16x4*)(wb + 102400 + i * 4) = o;
    } else if (gid < 76800) {
        const int i = gid - 51200;
        float4 v = ((const float4*)fc2_w)[i];
        u16x4 o = { f2bfbits(v.x), f2bfbits(v.y), f2bfbits(v.z), f2bfbits(v.w) };
        *(u16x4*)(wb + 204800 + i * 4) = o;
    } else if (gid < 77160) {
        const int i = gid - 76800;
        const int t = i / 40, c4 = (i % 40) * 4;
#pragma unroll
        for (int j = 0; j < 4; ++j) {
            const int c = c4 + j;
            cwT[t * DIM + c] = conv_w[c * 9 + t] * bn_g[c] * rsqrtf(1.0f + EPS);
        }
    } else if (gid < 269240) {
        const int i = gid - 77160;
        const int h = i / (NTOK * NTOK), r = i % (NTOK * NTOK);
        const int q = r / NTOK, k = r % NTOK;
        biasT[i] = abias[h * n_off + bidx[q * NTOK + k]] * 5.656854249492381f;
    }
}

// ---------------------------------------------------------------- LN kernels
__global__ __launch_bounds__(256) void ln1_win_kernel(
    const float* __restrict__ x, const float* __restrict__ g,
    const float* __restrict__ b, ushort* __restrict__ xn)
{
    const int row = blockIdx.x * 4 + (threadIdx.x >> 6);
    const int win = row / NTOK, tok = row % NTOK;
    const int bb = win / 25, wr = (win % 25) / 5, wc = win % 5;
    const int gh = wr * WS + tok / WS, gw = wc * WS + tok % WS;
    const bool valid = (gh < H_) && (gw < W_);
    const float* xrow = x + ((size_t)bb * L_ + (size_t)gh * W_ + gw) * DIM;
    const int lane = threadIdx.x & 63;
    float v0 = 0.f, v1 = 0.f, v2 = 0.f;
    if (valid) {
        v0 = xrow[lane];
        v1 = xrow[lane + 64];
        if (lane < 32) v2 = xrow[lane + 128];
    }
    float s  = v0 + v1 + v2;
    float sq = v0 * v0 + v1 * v1 + v2 * v2;
#pragma unroll
    for (int off = 32; off; off >>= 1) { s += __shfl_xor(s, off); sq += __shfl_xor(sq, off); }
    const float mean = s * (1.0f / DIM);
    const float var  = sq * (1.0f / DIM) - mean * mean;
    const float rs   = rsqrtf(var + EPS);
    ushort* orow = xn + (size_t)row * DIM;
    orow[lane]      = f2bfbits((v0 - mean) * rs * g[lane]      + b[lane]);
    orow[lane + 64] = f2bfbits((v1 - mean) * rs * g[lane + 64] + b[lane + 64]);
    if (lane < 32) orow[lane + 128] = f2bfbits((v2 - mean) * rs * g[lane + 128] + b[lane + 128]);
}

__global__ __launch_bounds__(256) void ln2_kernel(
    const float* __restrict__ x, const float* __restrict__ g,
    const float* __restrict__ b, ushort* __restrict__ xn)
{
    const int row = blockIdx.x * 4 + (threadIdx.x >> 6);
    const float* xrow = x + (size_t)row * DIM;
    const int lane = threadIdx.x & 63;
    float v0 = xrow[lane];
    float v1 = xrow[lane + 64];
    float v2 = (lane < 32) ? xrow[lane + 128] : 0.f;
    float s  = v0 + v1 + v2;
    float sq = v0 * v0 + v1 * v1 + v2 * v2;
#pragma unroll
    for (int off = 32; off; off >>= 1) { s += __shfl_xor(s, off); sq += __shfl_xor(sq, off); }
    const float mean = s * (1.0f / DIM);
    const float var  = sq * (1.0f / DIM) - mean * mean;
    const float rs   = rsqrtf(var + EPS);
    ushort* orow = xn + (size_t)row * DIM;
    orow[lane]      = f2bfbits((v0 - mean) * rs * g[lane]      + b[lane]);
    orow[lane + 64] = f2bfbits((v1 - mean) * rs * g[lane + 64] + b[lane + 64]);
    if (lane < 32) orow[lane + 128] = f2bfbits((v2 - mean) * rs * g[lane + 128] + b[lane + 128]);
}

// ---------------------------------------------------------------- MFMA GEMM
// C[m,n] = sum_k A[m,k] * Wb[n,k] + bias[n].  A, Wb bf16-bits.
// B (weights, L2-resident) double-buffered in LDS (4x wave reuse).
// A fragments loaded global->register directly (wave-exclusive rows),
// 2-step register pipeline to hide HBM latency.
#define GBM 128
#define GBN 160
#define GBK 32

template <int EPI>
__global__ __launch_bounds__(256, 3) void gemm_mfma(
    const ushort* __restrict__ A, const ushort* __restrict__ Wb,
    const float* __restrict__ bias, void* __restrict__ Cv,
    const float* __restrict__ extra, int M, int N, int K)
{
    __shared__ ushort Bs[2][GBN][40];
    const int tid = threadIdx.x;
    const int wv = tid >> 6, ln = tid & 63;
    const int g = ln >> 4, l15 = ln & 15;
    const int m0 = blockIdx.y * GBM, n0 = blockIdx.x * GBN;
    const int nk = K / GBK;
    f32x4 acc[2][10] = {};

    int am0 = m0 + wv * 32 + l15;      if (am0 >= M) am0 = M - 1;
    int am1 = m0 + wv * 32 + 16 + l15; if (am1 >= M) am1 = M - 1;
    const ushort* A0 = A + (size_t)am0 * K + g * 8;
    const ushort* A1 = A + (size_t)am1 * K + g * 8;

    const ushort* B0p = Wb + (size_t)(n0 + (tid >> 1)) * K + (tid & 1) * 16;
    const ushort* B1p = Wb + (size_t)(n0 + 128 + (tid >> 1)) * K + (tid & 1) * 16;

    int4 rb0a, rb0b, rb1a = {}, rb1b = {};
#define BGLOAD(ks) do { \
        rb0a = *(const int4*)(B0p + (ks)); rb0b = *(const int4*)(B0p + (ks) + 8); \
        if (tid < 64) { rb1a = *(const int4*)(B1p + (ks)); rb1b = *(const int4*)(B1p + (ks) + 8); } \
    } while (0)
#define BWRITE(nb) do { \
        *(int4*)&Bs[nb][tid >> 1][(tid & 1) * 16]     = rb0a; \
        *(int4*)&Bs[nb][tid >> 1][(tid & 1) * 16 + 8] = rb0b; \
        if (tid < 64) { \
            *(int4*)&Bs[nb][128 + (tid >> 1)][(tid & 1) * 16]     = rb1a; \
            *(int4*)&Bs[nb][128 + (tid >> 1)][(tid & 1) * 16 + 8] = rb1b; \
        } \
    } while (0)

    // prologue: B step 0 staged; A steps 0 and 1 in registers
    BGLOAD(0);
    s16x8 a0_c = *(const s16x8*)(A0);
    s16x8 a1_c = *(const s16x8*)(A1);
    s16x8 a0_n = a0_c, a1_n = a1_c;
    if (nk > 1) { a0_n = *(const s16x8*)(A0 + GBK); a1_n = *(const s16x8*)(A1 + GBK); }
    BWRITE(0);

    for (int s = 0; s < nk; ++s) {
        const int buf = s & 1;
        if (s + 1 < nk) BGLOAD((s + 1) * GBK);
        __syncthreads();
#pragma unroll
        for (int nt = 0; nt < 10; ++nt) {
            s16x8 bf = *(const s16x8*)&Bs[buf][nt * 16 + l15][g * 8];
            acc[0][nt] = __builtin_amdgcn_mfma_f32_16x16x32_bf16(a0_c, bf, acc[0][nt], 0, 0, 0);
            acc[1][nt] = __builtin_amdgcn_mfma_f32_16x16x32_bf16(a1_c, bf, acc[1][nt], 0, 0, 0);
        }
        a0_c = a0_n; a1_c = a1_n;
        if (s + 2 < nk) {
            a0_n = *(const s16x8*)(A0 + (s + 2) * GBK);
            a1_n = *(const s16x8*)(A1 + (s + 2) * GBK);
        }
        if (s + 1 < nk) BWRITE(buf ^ 1);
    }
#undef BGLOAD
#undef BWRITE

#pragma unroll
    for (int mt = 0; mt < 2; ++mt) {
#pragma unroll
        for (int nt = 0; nt < 10; ++nt) {
            const int n = n0 + nt * 16 + l15;
            const float bn = bias[n];
#pragma unroll
            for (int r = 0; r < 4; ++r) {
                const int m = m0 + wv * 32 + mt * 16 + g * 4 + r;
                if (m >= M) continue;
                const float val = acc[mt][nt][r] + bn;
                if (EPI == 0) {
                    ((ushort*)Cv)[(size_t)m * N + n] = f2bfbits(val);
                } else if (EPI == 1) {
                    const int win = m / NTOK, tok = m % NTOK;
                    const int bb = win / 25, wr = (win % 25) / 5, wc = win % 5;
                    const int gh = wr * WS + tok / WS, gw = wc * WS + tok % WS;
                    if (gh < H_ && gw < W_) {
                        const size_t off = ((size_t)bb * L_ + (size_t)gh * W_ + gw) * DIM + n;
                        ((float*)Cv)[off] = extra[off] + val;
                    }
                } else if (EPI == 2) {
                    const float ge = 0.5f * val * (1.0f + erff(val * 0.70710678118654752f));
                    ((ushort*)Cv)[(size_t)m * N + n] = f2bfbits(ge);
                } else {
                    const size_t off = (size_t)m * N + n;
                    ((float*)Cv)[off] = extra[off] + val;
                }
            }
        }
    }
}

// ---------------------------------------------------------------- attention
__global__ __launch_bounds__(256) void attn_mfma_kernel(
    const ushort* __restrict__ qkv, const float* __restrict__ biasT,
    ushort* __restrict__ out)
{
    __shared__ ushort Ks[208][40];
    __shared__ ushort VT[32][212];
    const int win = blockIdx.x / HEADS;
    const int h   = blockIdx.x % HEADS;
    const int tid = threadIdx.x;
    const size_t base = (size_t)win * NTOK;
    const ushort* qbase = qkv + base * 480 + h * 96;

    for (int e = tid; e < 208 * 4; e += 256) {
        const int row = e >> 2, part = e & 3;
        const int gr = row < NTOK ? row : NTOK - 1;
        *(int4*)&Ks[row][part * 8] = *(const int4*)(qbase + (size_t)gr * 480 + 32 + part * 8);
    }
    for (int e = tid; e < NTOK * 4; e += 256) {
        const int key = e >> 2, part = e & 3;
        int4 p = *(const int4*)(qbase + (size_t)key * 480 + 64 + part * 8);
        const ushort* u = (const ushort*)&p;
#pragma unroll
        for (int j = 0; j < 8; ++j) VT[part * 8 + j][key] = u[j];
    }
    for (int e = tid; e < 12 * 32; e += 256) VT[e & 31][NTOK + (e >> 5)] = 0;
    __syncthreads();

    const int wv = tid >> 6, ln = tid & 63, g = ln >> 4, l15 = ln & 15;
    const float cs = 0.17677669529663687f * 1.4426950408889634f;  // scale*log2e

    for (int qt = wv; qt < 13; qt += 4) {
        const int qr = qt * 16 + l15;
        const int qc = qr < NTOK ? qr : NTOK - 1;
        const s16x8 qf = *(const s16x8*)(qbase + (size_t)qc * 480 + g * 8);
        const float* bq = biasT + ((size_t)h * NTOK + qc) * NTOK;

        f32x4 S[13];
#pragma unroll
        for (int kt = 0; kt < 13; ++kt)
            S[kt] = *(const f32x4*)(bq + kt * 16 + g * 4);
#pragma unroll
        for (int kt = 0; kt < 13; ++kt) {
            const s16x8 kf = *(const s16x8*)&Ks[kt * 16 + l15][g * 8];
            S[kt] = __builtin_amdgcn_mfma_f32_16x16x32_bf16(kf, qf, S[kt], 0, 0, 0);
        }
        float mx = -1e30f;
#pragma unroll
        for (int kt = 0; kt < 13; ++kt) {
            const int kb = kt * 16 + g * 4;
#pragma unroll
            for (int r = 0; r < 4; ++r) {
                const float sv = (kb + r < NTOK) ? S[kt][r] * cs : -1e30f;
                S[kt][r] = sv;
                mx = fmaxf(mx, sv);
            }
        }
        mx = fmaxf(mx, __shfl_xor(mx, 16));
        mx = fmaxf(mx, __shfl_xor(mx, 32));

        float sum = 0.f;
        s16x4 P[13];
#pragma unroll
        for (int kt = 0; kt < 13; ++kt) {
            const float p0 = EXP2(S[kt][0] - mx);
            const float p1 = EXP2(S[kt][1] - mx);
            const float p2 = EXP2(S[kt][2] - mx);
            const float p3 = EXP2(S[kt][3] - mx);
            sum += (p0 + p1) + (p2 + p3);
            P[kt] = (s16x4){ (short)f2bfbits(p0), (short)f2bfbits(p1),
                             (short)f2bfbits(p2), (short)f2bfbits(p3) };
        }
        sum += __shfl_xor(sum, 16);
        sum += __shfl_xor(sum, 32);

        f32x4 o0 = {0.f,0.f,0.f,0.f}, o1 = {0.f,0.f,0.f,0.f};
#pragma unroll
        for (int kt = 0; kt < 13; ++kt) {
            const s16x4 vf0 = *(const s16x4*)&VT[l15][kt * 16 + g * 4];
            const s16x4 vf1 = *(const s16x4*)&VT[16 + l15][kt * 16 + g * 4];
            o0 = __builtin_amdgcn_mfma_f32_16x16x16bf16_1k(vf0, P[kt], o0, 0, 0, 0);
            o1 = __builtin_amdgcn_mfma_f32_16x16x16bf16_1k(vf1, P[kt], o1, 0, 0, 0);
        }
        if (qr < NTOK) {
            const float inv = 1.0f / sum;
            ushort* op = out + (base + qr) * DIM + h * KD;
            u16x4 w0 = { f2bfbits(o0[0] * inv), f2bfbits(o0[1] * inv),
                         f2bfbits(o0[2] * inv), f2bfbits(o0[3] * inv) };
            u16x4 w1 = { f2bfbits(o1[0] * inv), f2bfbits(o1[1] * inv),
                         f2bfbits(o1[2] * inv), f2bfbits(o1[3] * inv) };
            *(u16x4*)(op + g * 4)      = w0;
            *(u16x4*)(op + 16 + g * 4) = w1;
        }
    }
}

// ---------------------------------------------------------------- dw conv + BN
__global__ __launch_bounds__(256) void dwconv_bn_kernel(
    const float* __restrict__ xin, const float* __restrict__ cwT,
    const float* __restrict__ bnb, float* __restrict__ xout)
{
    const int gid = blockIdx.x * 256 + threadIdx.x;   // MROW*40
    const int pos = gid / 40, c4 = (gid % 40) * 4;
    const int bb = pos >> 12, hw = pos & 4095;
    const int hh = hw >> 6, ww = hw & 63;
    float4 acc = *(const float4*)&bnb[c4];
#pragma unroll
    for (int kh = -1; kh <= 1; ++kh) {
        const int ih = hh + kh;
        if (ih < 0 || ih >= H_) continue;
#pragma unroll
        for (int kw = -1; kw <= 1; ++kw) {
            const int iw = ww + kw;
            if (iw < 0 || iw >= W_) continue;
            const float4 xv = *(const float4*)&xin[((size_t)(bb << 12) + (ih << 6) + iw) * DIM + c4];
            const float4 wv = *(const float4*)&cwT[((kh + 1) * 3 + (kw + 1)) * DIM + c4];
            acc.x = fmaf(xv.x, wv.x, acc.x);
            acc.y = fmaf(xv.y, wv.y, acc.y);
            acc.z = fmaf(xv.z, wv.z, acc.z);
            acc.w = fmaf(xv.w, wv.w, acc.w);
        }
    }
    *(float4*)&xout[(size_t)pos * DIM + c4] = acc;
}

// ---------------------------------------------------------------- launch
extern "C" void kernel_launch(void* const* d_in, const int* in_sizes, int n_in,
                              void* d_out, int out_size, void* d_ws, size_t ws_size,
                              hipStream_t stream)
{
    const float* x      = (const float*)d_in[0];
    const float* ln1_g  = (const float*)d_in[1];
    const float* ln1_b  = (const float*)d_in[2];
    const float* qkv_w  = (const float*)d_in[3];
    const float* qkv_b  = (const float*)d_in[4];
    const float* proj_w = (const float*)d_in[5];
    const float* proj_b = (const float*)d_in[6];
    const float* abias  = (const float*)d_in[7];
    const float* conv_w = (const float*)d_in[8];
    const float* bn_g   = (const float*)d_in[9];
    const float* bn_b   = (const float*)d_in[10];
    const float* ln2_g  = (const float*)d_in[11];
    const float* ln2_b  = (const float*)d_in[12];
    const float* fc1_w  = (const float*)d_in[13];
    const float* fc1_b  = (const float*)d_in[14];
    const float* fc2_w  = (const float*)d_in[15];
    const float* fc2_b  = (const float*)d_in[16];
    const int*   bidx   = (const int*)d_in[17];
    const int    n_off  = in_sizes[7] / HEADS;

    char* ws = (char*)d_ws;
    // [0,          25,088,000)  xn  bf16 78400x160   (dead after qkv gemm)
    // [25,088,000, 100,352,000) qkv bf16 78400x480   (dead after attn)
    // [0,          83,886,080)  h   bf16 65536x640   (reuses xn+qkv)
    // [100,352,000,125,440,000) ao  bf16 78400x160   (dead after proj) / xn2
    // [125,440,000,126,208,320) biasT f32 5x196x196  (overlaps x1; attn reads
    //                            it before proj writes x1)
    // [125,440,000,167,383,040) x1  f32 65536x160    (dead after conv)
    // [167,383,040,167,997,440) wb  bf16 weights (qkv|proj|fc1|fc2)
    // [167,997,440,168,003,200) cwT f32 9x160 (BN-folded)
    ushort* xn    = (ushort*)(ws);
    ushort* qkv   = (ushort*)(ws + 25088000);
    ushort* ao    = (ushort*)(ws + 100352000);
    ushort* xn2   = (ushort*)(ws + 100352000);
    float*  biasT = (float*)(ws + 125440000);
    float*  x1    = (float*)(ws + 125440000);
    ushort* hbuf  = (ushort*)(ws);
    ushort* wb    = (ushort*)(ws + 167383040);
    float*  cwT   = (float*)(ws + 167997440);
    float*  x2    = (float*)d_out;
    float*  outp  = (float*)d_out;

    pre_kernel<<<dim3(1052), dim3(256), 0, stream>>>(
        qkv_w, proj_w, fc1_w, fc2_w, conv_w, bn_g, abias, bidx, wb, cwT, biasT, n_off);

    ln1_win_kernel<<<dim3(NROW / 4), dim3(256), 0, stream>>>(x, ln1_g, ln1_b, xn);

    gemm_mfma<0><<<dim3(480 / GBN, (NROW + GBM - 1) / GBM), dim3(256), 0, stream>>>(
        xn, wb, qkv_b, (void*)qkv, nullptr, NROW, 480, DIM);

    attn_mfma_kernel<<<dim3(NWIN * HEADS), dim3(256), 0, stream>>>(qkv, biasT, ao);

    gemm_mfma<1><<<dim3(DIM / GBN, (NROW + GBM - 1) / GBM), dim3(256), 0, stream>>>(
        ao, wb + 76800, proj_b, (void*)x1, x, NROW, DIM, DIM);

    dwconv_bn_kernel<<<dim3(MROW * 40 / 256), dim3(256), 0, stream>>>(
        x1, cwT, bn_b, x2);

    ln2_kernel<<<dim3(MROW / 4), dim3(256), 0, stream>>>(x2, ln2_g, ln2_b, xn2);

    gemm_mfma<2><<<dim3(HIDDEN / GBN, MROW / GBM), dim3(256), 0, stream>>>(
        xn2, wb + 102400, fc1_b, (void*)hbuf, nullptr, MROW, HIDDEN, DIM);

    gemm_mfma<3><<<dim3(DIM / GBN, MROW / GBM), dim3(256), 0, stream>>>(
        hbuf, wb + 204800, fc2_b, (void*)outp, x2, MROW, DIM, HIDDEN);
}